// Round 1
// 504.887 us; speedup vs baseline: 1.0426x; 1.0426x over previous
//
#include <hip/hip_runtime.h>
#include <cstdint>
#include <cstddef>
#include <cmath>

// ---------------------------------------------------------------------------
// DotProductAttention: out = softmax_causal((x@Q/32) @ (x@K)^T) @ (x@V)
//   B=4, S=4096, D=1024, fp32 in/out, bf16 MFMA compute.
// R6 changes vs R5 (526 us):
//   - PV GEMM (step 7) was the top dispatch at 134 us with Occupancy 11%:
//     grid (16,8,4)=512 blocks == exact residency capacity, and ids c,c+256
//     share blockIdx.x == mt -> each CU got two SAME-DEPTH causal blocks
//     (16:1 per-CU load imbalance; 11% occ == (2176/4096)*25% predicted).
//   - Fix: gemm_bt templated on BM; PV uses BM=128 (LDS 32 KB -> up to
//     5 blocks/CU) with a balanced 1D grid of 1024 blocks:
//     id = (hi:2|mid:5|g:3); mt = {31-g,16+g,15-g,g}[hi]; bz=mid&3,
//     nt=mid>>2. Stride-256 buddies (one CU) get constant total work
//     (66 K-units each); same-mt blocks share an XCD (id mod 8) for L2
//     Sb reuse; longest mts dispatch first.
//   - Softmax 256-pad remains >= new kend=(mt+1)*128 for all rows (safe).
// Workspace map (224 MB):
//   [0,64)   QKx bf16 [B*S][2048]  (Qx=+0, Kx=+1024, ld 2048)
//   [64,96)  Vxt bf16 [B][D][S]
//   [96,224) Sb bf16 [B][S][S]  -- early-phase reuse (all dead before Sb):
//       Vtmp@96 (32M), XB@128 (32M), WTqk@160 (4M), WTv@164 (2M)
// ---------------------------------------------------------------------------

typedef unsigned short u16;
typedef __bf16  bf16x8 __attribute__((ext_vector_type(8)));
typedef float   f32x4  __attribute__((ext_vector_type(4)));
typedef unsigned short u16x4 __attribute__((ext_vector_type(4)));

typedef __attribute__((address_space(1))) void gvoid;
typedef __attribute__((address_space(3))) void lvoid;

__device__ __forceinline__ u16 f2bf(float f) {
  union { float f; unsigned u; } v; v.f = f;
  unsigned u = v.u;
  u += 0x7FFFu + ((u >> 16) & 1u);   // round-to-nearest-even
  return (u16)(u >> 16);
}
__device__ __forceinline__ float bf2f(u16 h) {
  union { unsigned u; float f; } v; v.u = ((unsigned)h) << 16;
  return v.f;
}
__device__ __forceinline__ void async16(const void* g, void* l) {
  __builtin_amdgcn_global_load_lds((gvoid*)(void*)g, (lvoid*)l, 16, 0, 0);
}

// --------------------------- elementwise convert ---------------------------
__global__ void __launch_bounds__(256) cvt_f32_bf16(const float4* __restrict__ in,
                                                    u16* __restrict__ out, int n4) {
  int i = blockIdx.x * 256 + threadIdx.x;
  if (i >= n4) return;
  float4 v = in[i];
  u16x4 o = { f2bf(v.x), f2bf(v.y), f2bf(v.z), f2bf(v.w) };
  *(u16x4*)(out + 4 * (size_t)i) = o;
}

// ------------------------------- transpose ---------------------------------
__device__ __forceinline__ u16 to_bfs(float v, float s) { return f2bf(v * s); }
__device__ __forceinline__ u16 to_bfs(u16 v, float)     { return v; }

template <typename TIN>
__global__ void __launch_bounds__(256) transpose_to_bf16(
    const TIN* __restrict__ in, u16* __restrict__ out,
    int rows, int cols, long inStride, long outStride, float scale) {
  __shared__ u16 t[64][68];                 // stride 136B -> 2-way alias (free)
  int rt = blockIdx.x * 64, ct = blockIdx.y * 64;
  long ib = (long)blockIdx.z * inStride, ob = (long)blockIdx.z * outStride;
  int tx = threadIdx.x & 63, ty = threadIdx.x >> 6;
#pragma unroll
  for (int r = ty; r < 64; r += 4)
    t[r][tx] = to_bfs(in[ib + (long)(rt + r) * cols + ct + tx], scale);
  __syncthreads();
#pragma unroll
  for (int r = ty; r < 64; r += 4)
    out[ob + (long)(ct + r) * rows + rt + tx] = t[tx][r];
}

// ------------------------------- GEMM core ---------------------------------
// C[m][n] = alpha * sum_k A[m][k] * Bt[n][k]; A,Bt bf16 row-major.
// Block tile BM(M) x 128(N), BK=64 as two BK=32 LDS panels.
// 256 threads = 4 waves in 2x2; wave tile (BM/2)x64; (BM/32)x4 MFMAs/panel.
// TRI: blockIdx.x compacted causal grid (mt: 256-row units, nt: 128-col).
// CK:  causal PV, BM=128: balanced 1D grid (see header comment), k-limit
//      (mt+1)*128.
template <bool OUTF32, bool TRI, bool CK, int BM>
__global__ void __launch_bounds__(256, BM == 256 ? 2 : 4) gemm_bt(
    const u16* __restrict__ A, const u16* __restrict__ Bt, void* __restrict__ C,
    int K, int lda, int ldb, int ldc,
    long aStride, long bStride, long cStride, float alpha) {
  constexpr int MR = BM / 32;   // acc M-fragments per wave (8 or 4)
  constexpr int AQ = BM / 64;   // A staging chunks per thread per panel (4 or 2)
  int mt, nt, bz;
  if (TRI) {
    const int bid = blockIdx.x;           // C(m) = m*(m+1); 2m+2 blocks per m
    int m = (int)((sqrtf(4.0f * (float)bid + 1.0f) - 1.0f) * 0.5f);
    while ((m + 1) * (m + 2) <= bid) ++m;
    while (m * (m + 1) > bid) --m;
    mt = m; nt = bid - m * (m + 1);
    bz = blockIdx.z;
  } else if (CK) {
    // 1024 blocks; buddies {c,c+256,c+512,c+768} (one CU under round-robin)
    // receive mts {31-g, 16+g, 15-g, g}: per-CU work == 66 units, constant.
    // Same-mt blocks sit at ids == const (mod 8) -> same XCD -> L2 A-reuse.
    const int id = blockIdx.x;
    const int g = id & 7, mid = (id >> 3) & 31, hi = id >> 8;
    bz = mid & 3; nt = mid >> 2;
    mt = (hi == 0) ? 31 - g : (hi == 1) ? 16 + g : (hi == 2) ? 15 - g : g;
  } else {
    mt = blockIdx.x; nt = blockIdx.y; bz = blockIdx.z;
  }
  const int tid = threadIdx.x, wv = tid >> 6, ln = tid & 63;
  const u16* Ag = A + (long)bz * aStride + (long)(mt * BM) * lda;
  const u16* Bg = Bt + (long)bz * bStride + (long)(nt * 128) * ldb;

  __shared__ __align__(16) __bf16 As[2][BM * 32];
  __shared__ __align__(16) __bf16 Bs[2][128 * 32];

  f32x4 acc[MR][4];
#pragma unroll
  for (int i = 0; i < MR; ++i)
#pragma unroll
    for (int j = 0; j < 4; ++j)
#pragma unroll
      for (int r = 0; r < 4; ++r) acc[i][j][r] = 0.f;

  const int kend = CK ? (((mt + 1) * BM < K) ? (mt + 1) * BM : K) : K;
  const int wm = wv & 1, wn = wv >> 1;
  const int mrow = wm * (BM / 2), nrow = wn * 64;
  const int lr = ln & 15, quad = ln >> 4;

  // staging: A-tile BM*4 chunks of 16B, B-tile 512 chunks.
  // chunk c -> row=c>>2, logical col8 idx=c&3; swizzled GLOBAL col =
  // (c8i ^ ((row>>1)&3))*8 so that LDS slot (row,c8i) holds logical
  // column (c8i ^ swz(row)).
  long aOff[AQ]; int aLds[AQ];
#pragma unroll
  for (int q = 0; q < AQ; ++q) {
    int c = q * 256 + tid, row = c >> 2, c8i = c & 3;
    aOff[q] = (long)row * lda + ((c8i ^ ((row >> 1) & 3)) << 3);
    aLds[q] = c * 8;                       // elements
  }
  long bOff[2]; int bLds[2];
#pragma unroll
  for (int q = 0; q < 2; ++q) {
    int c = q * 256 + tid, row = c >> 2, c8i = c & 3;
    bOff[q] = (long)row * ldb + ((c8i ^ ((row >> 1) & 3)) << 3);
    bLds[q] = c * 8;
  }
  // read-side swizzle: row = (multiple of 64) + u*16 + lr ->
  // (row>>1)&3 == (lr>>1)&3, lane-constant across all fragments.
  const int swq = (quad ^ ((lr >> 1) & 3)) << 3;

  for (int k0 = 0; k0 < kend; k0 += 64) {
#pragma unroll
    for (int p = 0; p < 2; ++p) {
      const long kk = k0 + p * 32;
#pragma unroll
      for (int q = 0; q < AQ; ++q)
        async16(Ag + kk + aOff[q], (char*)As[p] + aLds[q] * 2);
#pragma unroll
      for (int q = 0; q < 2; ++q)
        async16(Bg + kk + bOff[q], (char*)Bs[p] + bLds[q] * 2);
    }
    __syncthreads();   // drains vmcnt before barrier
#pragma unroll
    for (int p = 0; p < 2; ++p) {
      bf16x8 af[MR], bfr[4];
#pragma unroll
      for (int u = 0; u < MR; ++u)
        af[u] = *(const bf16x8*)&As[p][(mrow + u * 16 + lr) * 32 + swq];
#pragma unroll
      for (int j = 0; j < 4; ++j)
        bfr[j] = *(const bf16x8*)&Bs[p][(nrow + j * 16 + lr) * 32 + swq];
#pragma unroll
      for (int u = 0; u < MR; ++u)
#pragma unroll
        for (int j = 0; j < 4; ++j)
          acc[u][j] = __builtin_amdgcn_mfma_f32_16x16x32_bf16(af[u], bfr[j], acc[u][j], 0, 0, 0);
    }
    __syncthreads();   // protect LDS before next refill
  }

  // epilogue: C/D layout col=lane&15, row=(lane>>4)*4+reg  [verified m89/m91]
  const long cb = (long)bz * cStride;
#pragma unroll
  for (int i = 0; i < MR; ++i) {
    int row0 = mt * BM + mrow + i * 16 + quad * 4;
#pragma unroll
    for (int j = 0; j < 4; ++j) {
      int col = nt * 128 + nrow + j * 16 + lr;
#pragma unroll
      for (int r = 0; r < 4; ++r) {
        float v = acc[i][j][r] * alpha;
        long idx = cb + (long)(row0 + r) * ldc + col;
        if (OUTF32) ((float*)C)[idx] = v;
        else        ((u16*)C)[idx]  = f2bf(v);
      }
    }
  }
}

// ------------------------------ row softmax --------------------------------
// One block per (row, batch). Pads [L, ceil256(L)) with zeros so the PV GEMM
// (128-row M-tiles, kend=(mt+1)*128 <= ceil256(row+1)) reads no garbage.
__global__ void __launch_bounds__(256) softmax_rows(u16* __restrict__ Sb,
                                                    long bStride, int S) {
  const int row = blockIdx.x;
  u16* p = Sb + (long)blockIdx.y * bStride + (long)row * S;
  const int L = row + 1;
  const int Lpad = (L + 255) & ~255;
  const int tid = threadIdx.x, ln = tid & 63, wv = tid >> 6;
  __shared__ float red[8];

  float vals[16];
  float lmax = -3.4e38f;
#pragma unroll
  for (int k = 0; k < 16; ++k) {
    int j = tid + k * 256;
    if (j < L) { float v = bf2f(p[j]); vals[k] = v; lmax = fmaxf(lmax, v); }
  }
#pragma unroll
  for (int o = 32; o > 0; o >>= 1) lmax = fmaxf(lmax, __shfl_down(lmax, o));
  if (ln == 0) red[wv] = lmax;
  __syncthreads();
  float m = fmaxf(fmaxf(red[0], red[1]), fmaxf(red[2], red[3]));

  float lsum = 0.f;
#pragma unroll
  for (int k = 0; k < 16; ++k) {
    int j = tid + k * 256;
    if (j < L) { float e = __expf(vals[k] - m); vals[k] = e; lsum += e; }
  }
#pragma unroll
  for (int o = 32; o > 0; o >>= 1) lsum += __shfl_down(lsum, o);
  __syncthreads();
  if (ln == 0) red[wv] = lsum;
  __syncthreads();
  float inv = 1.f / (red[0] + red[1] + red[2] + red[3]);
#pragma unroll
  for (int k = 0; k < 16; ++k) {
    int j = tid + k * 256;
    if (j < L) p[j] = f2bf(vals[k] * inv);
  }
  for (int j = L + tid; j < Lpad; j += 256) p[j] = 0;
}

// ------------------------------- launcher ----------------------------------
extern "C" void kernel_launch(void* const* d_in, const int* in_sizes, int n_in,
                              void* d_out, int out_size, void* d_ws, size_t ws_size,
                              hipStream_t stream) {
  const float* x = (const float*)d_in[0];
  const float* Q = (const float*)d_in[1];
  const float* K = (const float*)d_in[2];
  const float* V = (const float*)d_in[3];
  float* out = (float*)d_out;

  constexpr int  Bb = 4, S = 4096, D = 1024;
  constexpr long MB = 1024 * 1024;
  if (ws_size < (size_t)(224 * MB)) return;

  char* ws = (char*)d_ws;
  u16* QKx  = (u16*)(ws);             // [B*S][2048]  Qx=+0, Kx=+1024
  u16* Vxt  = (u16*)(ws + 64 * MB);   // [B][D][S]
  u16* Sb   = (u16*)(ws + 96 * MB);   // [B][S][S]
  u16* Vtmp = (u16*)(ws + 96 * MB);   // [B][S][D]   (dead before Sb written)
  u16* XB   = (u16*)(ws + 128 * MB);  // x bf16      (dead before Sb written)
  u16* WTqk = (u16*)(ws + 160 * MB);  // [2048][1024]
  u16* WTv  = (u16*)(ws + 164 * MB);  // [1024][1024]

  const long SD = (long)S * D, SS = (long)S * S;

  // 1. x -> bf16
  cvt_f32_bf16<<<dim3((Bb * S * D / 4) / 256), 256, 0, stream>>>(
      (const float4*)x, XB, Bb * S * D / 4);

  // 2. weight transposes (fp32 [k][n] -> bf16 [n][k]); 1/32 folded into Qt
  transpose_to_bf16<float><<<dim3(16, 16, 1), 256, 0, stream>>>(
      Q, WTqk, 1024, 1024, 0, 0, 0.03125f);
  transpose_to_bf16<float><<<dim3(16, 16, 1), 256, 0, stream>>>(
      K, WTqk + 1024 * 1024, 1024, 1024, 0, 0, 1.0f);
  transpose_to_bf16<float><<<dim3(16, 16, 1), 256, 0, stream>>>(
      V, WTv, 1024, 1024, 0, 0, 1.0f);

  // 3a. fused Q,K projection -> QKx [B*S][2048]   (M=16384 -> 64 m-tiles)
  gemm_bt<false, false, false, 256><<<dim3(64, 16, 1), 256, 0, stream>>>(
      XB, WTqk, QKx, 1024, 1024, 1024, 2048, 0, 0, 0, 1.0f);
  // 3b. V projection -> Vtmp
  gemm_bt<false, false, false, 256><<<dim3(64, 8, 1), 256, 0, stream>>>(
      XB, WTv, Vtmp, 1024, 1024, 1024, 1024, 0, 0, 0, 1.0f);

  // 4. Vtmp [b][s][d] -> Vxt [b][d][s]
  transpose_to_bf16<u16><<<dim3(64, 16, Bb), 256, 0, stream>>>(
      Vtmp, Vxt, S, D, SD, SD, 1.0f);

  // 5. causal scores: Sb = Qx @ Kx^T, TRI grid (16 m-tiles x up-to-32 n-tiles
  //    = 272 blocks/batch). QKx batch stride = S*2048 = 2*SD.
  gemm_bt<false, true, false, 256><<<dim3(272, 1, Bb), 256, 0, stream>>>(
      QKx, QKx + 1024, Sb, 1024, 2048, 2048, S, 2 * SD, 2 * SD, SS, 1.0f);

  // 6. row softmax in place (zero-pads rows to 256 boundary)
  softmax_rows<<<dim3(S, Bb), 256, 0, stream>>>(Sb, SS, S);

  // 7. out = P @ Vxt^T (causal k-limit; balanced 1D grid, 1024 blocks of
  //    128x128; batch/nt/mt decoded in-kernel)
  gemm_bt<true, false, true, 128><<<dim3(1024, 1, 1), 256, 0, stream>>>(
      Sb, Vxt, out, S, S, S, D, SS, SD, SD, 1.0f);
}